// Round 5
// baseline (3744.658 us; speedup 1.0000x reference)
//
#include <hip/hip_runtime.h>
#include <stdint.h>
#include <math.h>

#define NB 64
#define NT 512
#define NF 128
#define NH 512
#define NO 128
#define HSTR 520   // LDS A-tile row stride in shorts (512 + 8 pad)

typedef short  s16x8  __attribute__((ext_vector_type(8)));   // 8 bf16
typedef float  f32x4  __attribute__((ext_vector_type(4)));   // 16x16 acc
typedef float  f32x16 __attribute__((ext_vector_type(16)));  // 32x32 acc (head)

// ---------------- workspace layout (bytes) ----------------
#define OFF_XBF   ((size_t)0)                      // B*T*F bf16 = 8 MB
#define OFF_WOUT  ((size_t)(8u<<20))               // O*H bf16 = 128 KB
#define OFF_SEQ0  ((size_t)(12u<<20))              // B*T*H bf16 = 32 MB
#define OFF_SEQ1  (OFF_SEQ0 + ((size_t)32u<<20))
#define OFF_SEQ2  (OFF_SEQ1 + ((size_t)32u<<20))
#define OFF_FLAGS (OFF_SEQ2 + ((size_t)32u<<20))
// flag dword layout (per-producer lines 64B apart — r2 lesson):
//   [    0 .. 3072)  rec fast lines (XCD L2, plain-store/sc0-load)
//   [ 4096 .. 7168)  rec backup lines (LLC/agent)
//   [ 8192 ..11264)  inter-layer lines (LLC/agent)
//   [12288 ..12480)  xcd handshake map

#define SMEM_BYTES 88064   // > 80 KB -> exactly 1 WG per CU (160 KB LDS pool)
#define POLL_BUDGET 1024   // bounded fast poll before permanent LLC fallback

__device__ __forceinline__ unsigned short f2bf(float f) {
  unsigned int u = __float_as_uint(f);
  u += 0x7fffu + ((u >> 16) & 1u);   // RNE
  return (unsigned short)(u >> 16);
}

__device__ __forceinline__ unsigned int ld_flag(unsigned int* p) {
  return __hip_atomic_load(p, __ATOMIC_RELAXED, __HIP_MEMORY_SCOPE_AGENT);
}

// proven LLC path: lanes 0..15 each watch one 64B-spread line; whole wave
// returns when all 16 lines >= tgt.
__device__ __forceinline__ void pollgrp_glb(unsigned int* base, unsigned int tgt, int lane) {
  bool done = (lane >= 16);
  for (;;) {
    if (!done && ld_flag(base + lane*16) >= tgt) done = true;
    if (__all(done)) return;
    __builtin_amdgcn_s_sleep(1);
  }
}

// fast path: flags written by PLAIN stores (land in XCD L2, same channel as
// the data); consumer reads with sc0 load = L1-bypass, served by local L2.
// BOUNDED — liveness never depends on it; returns false on timeout.
__device__ __forceinline__ bool pollgrp_l2(unsigned int* base, unsigned int tgt, int lane) {
  bool done = (lane >= 16);
  for (int it = 0; it < POLL_BUDGET; ++it) {
    if (!done) {
      unsigned int v;
      unsigned int* p = base + lane*16;
      asm volatile("global_load_dword %0, %1, off sc0\n\t"
                   "s_waitcnt vmcnt(0)"
                   : "=&v"(v) : "v"(p) : "memory");
      if (v >= tgt) done = true;
    }
    if (__all(done)) return true;
    __builtin_amdgcn_s_sleep(1);
  }
  return false;
}

__device__ __forceinline__ float sigmoid_f(float x) { return 1.f / (1.f + __expf(-x)); }
__device__ __forceinline__ float tanh_f(float x)    { return 1.f - 2.f / (__expf(2.f*x) + 1.f); }

// ---------------------------------------------------------------------------
// Persistent wavefront-pipelined GRU. 256 WGs (1/CU); bid%8>=6 exit.
// Group (layer,bq) = 16 col-slice WGs co-located on one XCD (verified at
// startup via HW_REG_XCC_ID handshake — r4 counters prove it engages).
// Fast mode: plain data+flag stores into the XCD L2 (group coherence pt);
// consumers poll flags with bounded sc0 loads, LLC backup for liveness.
// KEY r5 CHANGE: wave 5's inter-layer LLC republish is SOFTWARE-PIPELINED —
// it reads h(t-1) from a double-buffered LDS copy and only ISSUES the
// sc0 sc1 stores; the vmcnt(0) drain happens one full step later, so no
// wave ever holds barrier B2 on an LLC round trip.
// Also: producers zero their fast flag line at startup (plain store) before
// the handshake, killing cross-dispatch stale-L2 flag copies.
// Invariant both modes: glb value v  =>  rows 0..v-1 LLC-visible.
// ---------------------------------------------------------------------------
__global__ __launch_bounds__(384, 1)
void gru_persist(const unsigned short* __restrict__ xbf,
                 unsigned short* __restrict__ seq0,
                 unsigned short* __restrict__ seq1,
                 unsigned short* __restrict__ seq2,
                 unsigned int* __restrict__ flags,
                 const float* __restrict__ Wih0, const float* __restrict__ Whh0,
                 const float* __restrict__ bih0, const float* __restrict__ bhh0,
                 const float* __restrict__ Wih1, const float* __restrict__ Whh1,
                 const float* __restrict__ bih1, const float* __restrict__ bhh1,
                 const float* __restrict__ Wih2, const float* __restrict__ Whh2,
                 const float* __restrict__ bih2, const float* __restrict__ bhh2)
{
  extern __shared__ char smem[];
  __shared__ unsigned int s_fast;
  unsigned short* hA = (unsigned short*)smem;                  // 16 x 520 shorts
  unsigned short* xA = (unsigned short*)(smem + 16640);        // 16 x 520 shorts
  float (*xpL)[3][16][33] = (float (*)[3][16][33])(smem + 33280); // 2 slots
  float (*rzL)[16][33]    = (float (*)[16][33])(smem + 45952);    // r/z
  unsigned short (*hout)[512] = (unsigned short (*)[512])(smem + 50176); // 2 x 1 KB

  const int tid  = threadIdx.x;
  const int wid  = tid >> 6;
  const int lane = tid & 63;
  const int col  = lane & 15;     // n / m index
  const int quad = lane >> 4;     // k-group / row-quad

  const int bid  = blockIdx.x;
  const int pxcd = bid & 7;       // presumed XCD under round-robin dispatch
  if (pxcd >= 6) return;          // 64 dummies (XCDs 6,7 idle)
  const int wslot = bid >> 3;              // 0..31
  const int gid  = pxcd*2 + (wslot >> 4);  // 0..11 == l*4+bq
  const int cq   = wslot & 15;             // col slice
  const int l    = gid >> 2;               // layer 0..2
  const int bq   = gid & 3;                // batch quarter
  const int c0 = cq * 32;
  const int b0 = bq * 16;

  unsigned int* recbase = flags + gid*16*16;              // fast rec lines (L2)
  unsigned int* bkpbase = flags + 4096 + gid*16*16;       // backup rec lines (LLC)
  unsigned int* glbbase = flags + 8192 + gid*16*16;       // inter-layer lines (LLC)
  unsigned int* prvbase = (l > 0) ? (flags + 8192 + (gid-4)*16*16) : glbbase;
  unsigned int* xcdmap  = flags + 12288;

  // ---- startup: overwrite our fast flag line (kills stale L2 copy from a
  // previous dispatch), THEN announce ourselves. Consumers poll the fast
  // line only after the handshake, so they always see the fresh zero.
  // hwreg imm 63508 = size-1(31)<<11 | offset(0)<<6 | id 20 (HW_REG_XCC_ID)
  unsigned int myxcd = (__builtin_amdgcn_s_getreg(63508) & 7u) + 1u;
  if (tid == 0) {
    *(volatile unsigned int*)(recbase + cq*16) = 0u;
    asm volatile("s_waitcnt vmcnt(0)" ::: "memory");   // zero is in L2
    __hip_atomic_store(&xcdmap[gid*16 + cq], myxcd,
                       __ATOMIC_RELAXED, __HIP_MEMORY_SCOPE_AGENT);
    unsigned int ref = 0, same = 1;
    for (int m = 0; m < 16; ++m) {
      unsigned int v;
      do { v = ld_flag(&xcdmap[gid*16 + m]); } while (v == 0);
      if (m == 0) ref = v; else same &= (v == ref);
    }
    // foreign probe: group on a DIFFERENT presumed XCD must differ, else
    // the register is constant/broken -> distrust, slow path.
    int fg = (gid + 2) % 12;
    unsigned int fv;
    do { fv = ld_flag(&xcdmap[fg*16 + 0]); } while (fv == 0);
    s_fast = (same && (fv != ref)) ? 1u : 0u;
  }
  __syncthreads();
  const bool fastp = (s_fast != 0);

  unsigned short* seqw = (l==0) ? seq0 : (l==1) ? seq1 : seq2;
  const unsigned short* seqr = (l==1) ? seq0 : (l==2) ? seq1 : (const unsigned short*)0;

  const bool isrec = (wid < 3);
  const int  g     = isrec ? wid : wid - 3;

  const float* Whh = (l==0)?Whh0:(l==1)?Whh1:Whh2;
  const float* Wih = (l==0)?Wih0:(l==1)?Wih1:Wih2;
  const float* bhh = (l==0)?bhh0:(l==1)?bhh1:bhh2;
  const float* bih = (l==0)?bih0:(l==1)?bih1:bih2;

  const float* Wsrc = isrec ? Whh : Wih;
  const int K   = isrec ? NH : ((l==0) ? NF : NH);
  const int KT  = K >> 5;                 // 16 (K=512) or 4 (K=128)
  const int KTx = (l==0) ? 4 : 16;        // xp tile count
  const int xrow = (l==0) ? NF : NH;      // xp source row length (shorts)

  // ---- preload weight slice into regs (B-frag order), bf16 ----
  s16x8 wr0[16], wr1[16];
  #pragma unroll
  for (int kt = 0; kt < 16; ++kt) {
    if (kt < KT) {
      const float* s0 = Wsrc + (size_t)(g*NH + c0 +      col) * K + kt*32 + quad*8;
      const float* s1 = Wsrc + (size_t)(g*NH + c0 + 16 + col) * K + kt*32 + quad*8;
      s16x8 w0, w1;
      #pragma unroll
      for (int j = 0; j < 8; ++j) { w0[j] = (short)f2bf(s0[j]); w1[j] = (short)f2bf(s1[j]); }
      wr0[kt] = w0; wr1[kt] = w1;
    } else { wr0[kt] = (s16x8)0; wr1[kt] = (s16x8)0; }
  }
  const float* bb = isrec ? bhh : bih;
  const float bias0 = bb[g*NH + c0 +      col];
  const float bias1 = bb[g*NH + c0 + 16 + col];

  // stage a 16-row A-tile (rows b0..b0+15, time `step`) into LDS.
  auto stage_tile = [&](unsigned short* dst, const unsigned short* srcbase,
                        int rowlen, int step, int half) {
    const int sr = (half << 3) + (lane >> 3);
    const int sc = lane & 7;
    const unsigned short* src = srcbase + ((size_t)(b0 + sr)*NT + step)*rowlen;
    const int nld = rowlen >> 6;
    s16x8 tmp[8];
    #pragma unroll
    for (int i = 0; i < 8; ++i) if (i < nld) tmp[i] = *(const s16x8*)(src + (i*8 + sc)*8);
    #pragma unroll
    for (int i = 0; i < 8; ++i) if (i < nld) *(s16x8*)&dst[sr*HSTR + (i*8 + sc)*8] = tmp[i];
  };

  // ---- prologue (all inter-layer waits: proven LLC protocol) ----
  if (!isrec) {
    if (l > 0) pollgrp_glb(prvbase, 1u, lane);
    asm volatile("" ::: "memory");
    f32x4 a0 = {0.f,0.f,0.f,0.f}, a1 = {0.f,0.f,0.f,0.f};
    const unsigned short* ar = (l==0)
        ? xbf  + (size_t)(b0+col)*NT*NF + quad*8
        : seqr + (size_t)(b0+col)*NT*NH + quad*8;
    #pragma unroll
    for (int kt = 0; kt < 16; ++kt) if (kt < KTx) {
      s16x8 a = *(const s16x8*)(ar + kt*32);
      a0 = __builtin_amdgcn_mfma_f32_16x16x32_bf16(a, wr0[kt], a0, 0, 0, 0);
      a1 = __builtin_amdgcn_mfma_f32_16x16x32_bf16(a, wr1[kt], a1, 0, 0, 0);
    }
    #pragma unroll
    for (int i = 0; i < 4; ++i) {
      int row = quad*4 + i;
      xpL[0][g][row][col]      = a0[i] + bias0;
      xpL[0][g][row][col + 16] = a1[i] + bias1;
    }
  } else if (wid < 2) {
    if (l > 0) pollgrp_glb(prvbase, 2u, lane);
    asm volatile("" ::: "memory");
    stage_tile(xA, (l==0) ? xbf : seqr, xrow, 1, wid);
  }
  __syncthreads();

  float hp0[4] = {0.f,0.f,0.f,0.f}, hp1[4] = {0.f,0.f,0.f,0.f};  // n-wave h state
  bool l2poll = fastp;   // per-wave adaptive demotion to LLC backup

  for (int t = 0; t < NT; ++t) {
    const int slot2 = t & 1;
    const int nslot = slot2 ^ 1;

    f32x4 a0 = {0.f,0.f,0.f,0.f}, a1 = {0.f,0.f,0.f,0.f};

    // ---------------- phase 1: pure LDS -> MFMA compute ----------------
    if (isrec) {
      if (t > 0) {
        #pragma unroll
        for (int kt = 0; kt < 16; ++kt) {
          s16x8 a = *(const s16x8*)&hA[col*HSTR + kt*32 + quad*8];
          a0 = __builtin_amdgcn_mfma_f32_16x16x32_bf16(a, wr0[kt], a0, 0, 0, 0);
          a1 = __builtin_amdgcn_mfma_f32_16x16x32_bf16(a, wr1[kt], a1, 0, 0, 0);
        }
      }
      if (g < 2) {       // r/z: sigmoid -> LDS
        #pragma unroll
        for (int i = 0; i < 4; ++i) {
          int row = quad*4 + i;
          float p0 = a0[i] + xpL[slot2][g][row][col]      + bias0;
          float p1 = a1[i] + xpL[slot2][g][row][col + 16] + bias1;
          rzL[g][row][col]      = sigmoid_f(p0);
          rzL[g][row][col + 16] = sigmoid_f(p1);
        }
      } else {           // n: keep pre-activation hn (+bhh_n) in regs
        #pragma unroll
        for (int i = 0; i < 4; ++i) { a0[i] += bias0; a1[i] += bias1; }
      }
    } else if (t + 1 < NT) {   // xp waves: xp(t+1) from xA -> xpL[nslot]
      #pragma unroll
      for (int kt = 0; kt < 16; ++kt) if (kt < KTx) {
        s16x8 a = *(const s16x8*)&xA[col*HSTR + kt*32 + quad*8];
        a0 = __builtin_amdgcn_mfma_f32_16x16x32_bf16(a, wr0[kt], a0, 0, 0, 0);
        a1 = __builtin_amdgcn_mfma_f32_16x16x32_bf16(a, wr1[kt], a1, 0, 0, 0);
      }
      #pragma unroll
      for (int i = 0; i < 4; ++i) {
        int row = quad*4 + i;
        xpL[nslot][g][row][col]      = a0[i] + bias0;
        xpL[nslot][g][row][col + 16] = a1[i] + bias1;
      }
    }
    __syncthreads();   // B1

    // ---------------- phase 2 ----------------
    if (wid == 2) {      // n-wave: gate combine, h update, store, flags
      #pragma unroll
      for (int i = 0; i < 4; ++i) {
        int row = quad*4 + i;
        float xn0 = xpL[slot2][2][row][col];
        float xn1 = xpL[slot2][2][row][col + 16];
        float rt0 = rzL[0][row][col],      rt1 = rzL[0][row][col + 16];
        float zt0 = rzL[1][row][col],      zt1 = rzL[1][row][col + 16];
        float nv0 = tanh_f(xn0 + rt0 * a0[i]);
        float nv1 = tanh_f(xn1 + rt1 * a1[i]);
        float h0 = (1.f - zt0)*nv0 + zt0*hp0[i];
        float h1 = (1.f - zt1)*nv1 + zt1*hp1[i];
        hp0[i] = h0; hp1[i] = h1;
        hout[slot2][row*32 + col]      = f2bf(h0);
        hout[slot2][row*32 + col + 16] = f2bf(h1);
      }
      asm volatile("s_waitcnt lgkmcnt(0)" ::: "memory");
      int srow = lane >> 2, sch = lane & 3;
      s16x8 hv = *(const s16x8*)&hout[slot2][srow*32 + sch*8];
      unsigned short* p = seqw + ((size_t)(b0+srow)*NT + t)*NH + c0 + sch*8;
      unsigned int fv = (unsigned int)(t + 1);
      if (fastp) {
        // plain store: lands in this XCD's L2 (the group coherence point)
        *(s16x8*)p = hv;
        asm volatile("s_waitcnt vmcnt(0)" ::: "memory");   // L2 ack only
        if (lane == 0) {
          // plain flag store — same channel as the data (XCD L2)
          *(volatile unsigned int*)(recbase + cq*16) = fv;
          __hip_atomic_store(bkpbase + cq*16, fv,
                             __ATOMIC_RELAXED, __HIP_MEMORY_SCOPE_AGENT);
        }
        // inter-layer LLC republish: wave 5, pipelined one step behind
      } else {
        // baseline device-scope protocol (spread lines)
        asm volatile("global_store_dwordx4 %0, %1, off sc0 sc1" :: "v"(p), "v"(hv) : "memory");
        asm volatile("s_waitcnt vmcnt(0)" ::: "memory");
        if (lane == 0) {
          __hip_atomic_store(bkpbase + cq*16, fv,
                             __ATOMIC_RELAXED, __HIP_MEMORY_SCOPE_AGENT);
          if (l < 2)
            __hip_atomic_store(glbbase + cq*16, fv,
                               __ATOMIC_RELAXED, __HIP_MEMORY_SCOPE_AGENT);
        }
      }
    } else if (wid < 2) {        // waves 0,1: poll rec flags, stage hA halves
      if (t + 1 < NT) {
        unsigned int tgt = (unsigned)(t + 1);
        if (l2poll) {
          bool ok = pollgrp_l2(recbase, tgt, lane);
          if (!ok) { pollgrp_glb(bkpbase, tgt, lane); l2poll = false; }
        } else {
          pollgrp_glb(bkpbase, tgt, lane);
        }
        asm volatile("" ::: "memory");
        stage_tile(hA, seqw, NH, t, wid);
      }
    } else if (wid == 3 || wid == 4) {   // poll prevglb, stage xA halves
      if (t + 2 < NT) {
        if (l > 0) pollgrp_glb(prvbase, (unsigned)(t + 3), lane);
        asm volatile("" ::: "memory");
        stage_tile(xA, (l==0) ? xbf : seqr, xrow, t + 2, wid - 3);
      }
    } else {   // wid == 5: PIPELINED inter-layer republish (fast mode)
      if (fastp && l < 2 && t >= 1) {
        // (a) drain stores issued LAST step (a full step ago -> ~free)
        asm volatile("s_waitcnt vmcnt(0)" ::: "memory");
        // (b) publish flag for the row drained in (a): rows <= t-2 visible
        if (t >= 2 && lane == 0)
          __hip_atomic_store(glbbase + cq*16, (unsigned)(t - 1),
                             __ATOMIC_RELAXED, __HIP_MEMORY_SCOPE_AGENT);
        // (c) read h(t-1) from the LDS slot wave2 filled last step, and
        //     ISSUE the LLC stores without waiting.
        int srow = lane >> 2, sch = lane & 3;
        s16x8 hv2 = *(const s16x8*)&hout[(t - 1) & 1][srow*32 + sch*8];
        unsigned short* ps = seqw + ((size_t)(b0+srow)*NT + (t-1))*NH + c0 + sch*8;
        asm volatile("global_store_dwordx4 %0, %1, off sc0 sc1" :: "v"(ps), "v"(hv2) : "memory");
      }
    }
    __syncthreads();   // B2
  }

  // epilogue: fast mode finishes the republish tail (rows NT-2, NT-1)
  if (wid == 5 && fastp && l < 2) {
    asm volatile("s_waitcnt vmcnt(0)" ::: "memory");   // row NT-2 drained
    if (lane == 0)
      __hip_atomic_store(glbbase + cq*16, (unsigned)(NT - 1),
                         __ATOMIC_RELAXED, __HIP_MEMORY_SCOPE_AGENT);
    int srow = lane >> 2, sch = lane & 3;
    s16x8 hv2 = *(const s16x8*)&hout[(NT - 1) & 1][srow*32 + sch*8];
    unsigned short* ps = seqw + ((size_t)(b0+srow)*NT + (NT-1))*NH + c0 + sch*8;
    asm volatile("global_store_dwordx4 %0, %1, off sc0 sc1" :: "v"(ps), "v"(hv2) : "memory");
    asm volatile("s_waitcnt vmcnt(0)" ::: "memory");
    if (lane == 0)
      __hip_atomic_store(glbbase + cq*16, (unsigned)NT,
                         __ATOMIC_RELAXED, __HIP_MEMORY_SCOPE_AGENT);
  }
}

// ---------------- head GEMM: out[bt][o] = seq2[bt][:] . Wout[o][:] + bout ----
__global__ __launch_bounds__(256)
void head_gemm(const unsigned short* __restrict__ seq2,
               const unsigned short* __restrict__ woutb,
               const float* __restrict__ bout,
               float* __restrict__ out)
{
  int tid = threadIdx.x;
  int wv = tid >> 6, lane = tid & 63;
  int col = lane & 31, khi = lane >> 5;
  int id = blockIdx.x*4 + wv;
  int mt = id >> 2, nt = id & 3;
  int m0 = mt*32, n0 = nt*32;
  const unsigned short* arow = seq2  + (size_t)(m0 + col)*NH + (khi << 3);
  const unsigned short* brow = woutb + (size_t)(n0 + col)*NH + (khi << 3);
  f32x16 acc;
  #pragma unroll
  for (int i = 0; i < 16; ++i) acc[i] = 0.f;
  #pragma unroll 8
  for (int kt = 0; kt < 32; ++kt) {
    s16x8 a = *(const s16x8*)(arow + kt*16);
    s16x8 b = *(const s16x8*)(brow + kt*16);
    acc = __builtin_amdgcn_mfma_f32_32x32x16_bf16(a, b, acc, 0, 0, 0);
  }
  float bo = bout[n0 + col];
  #pragma unroll
  for (int r = 0; r < 16; ++r) {
    int row = (r & 3) + ((r >> 2) << 3) + (khi << 2);
    out[(size_t)(m0 + row)*NO + n0 + col] = acc[r] + bo;
  }
}

__global__ void cast_f32_bf16(const float* __restrict__ src,
                              unsigned short* __restrict__ dst, int n) {
  int i = blockIdx.x*blockDim.x + threadIdx.x;
  int stride = gridDim.x*blockDim.x;
  for (; i < n; i += stride) dst[i] = f2bf(src[i]);
}

extern "C" void kernel_launch(void* const* d_in, const int* in_sizes, int n_in,
                              void* d_out, int out_size, void* d_ws, size_t ws_size,
                              hipStream_t stream) {
  (void)in_sizes; (void)n_in; (void)out_size; (void)ws_size;
  const float* x    = (const float*)d_in[0];
  const float* Wih0 = (const float*)d_in[1];
  const float* Whh0 = (const float*)d_in[2];
  const float* bih0 = (const float*)d_in[3];
  const float* bhh0 = (const float*)d_in[4];
  const float* Wih1 = (const float*)d_in[5];
  const float* Whh1 = (const float*)d_in[6];
  const float* bih1 = (const float*)d_in[7];
  const float* bhh1 = (const float*)d_in[8];
  const float* Wih2 = (const float*)d_in[9];
  const float* Whh2 = (const float*)d_in[10];
  const float* bih2 = (const float*)d_in[11];
  const float* bhh2 = (const float*)d_in[12];
  const float* Wout = (const float*)d_in[13];
  const float* bout = (const float*)d_in[14];

  char* ws = (char*)d_ws;
  unsigned short* xbf  = (unsigned short*)(ws + OFF_XBF);
  unsigned short* wob  = (unsigned short*)(ws + OFF_WOUT);
  unsigned short* seq0 = (unsigned short*)(ws + OFF_SEQ0);
  unsigned short* seq1 = (unsigned short*)(ws + OFF_SEQ1);
  unsigned short* seq2 = (unsigned short*)(ws + OFF_SEQ2);
  unsigned int*   flg  = (unsigned int*)(ws + OFF_FLAGS);

  // allow >64KB dynamic LDS (idempotent, capture-safe)
  (void)hipFuncSetAttribute((const void*)gru_persist,
                            hipFuncAttributeMaxDynamicSharedMemorySize, 160*1024);

  hipMemsetAsync(ws + OFF_FLAGS, 0, 65536, stream);
  cast_f32_bf16<<<512, 256, 0, stream>>>(x, xbf, NB*NT*NF);
  cast_f32_bf16<<<64, 256, 0, stream>>>(Wout, wob, NO*NH);
  gru_persist<<<256, 384, SMEM_BYTES, stream>>>(xbf, seq0, seq1, seq2, flg,
      Wih0, Whh0, bih0, bhh0, Wih1, Whh1, bih1, bhh1, Wih2, Whh2, bih2, bhh2);
  head_gemm<<<1024, 256, 0, stream>>>(seq2, wob, bout, (float*)d_out);
}

// Round 6
// 2970.985 us; speedup vs baseline: 1.2604x; 1.2604x over previous
//
#include <hip/hip_runtime.h>
#include <stdint.h>
#include <math.h>

#define NB 64
#define NT 512
#define NF 128
#define NH 512
#define NO 128
#define HSTR 520   // LDS A-tile row stride in shorts (512 + 8 pad)

typedef short  s16x8  __attribute__((ext_vector_type(8)));   // 8 bf16
typedef float  f32x4  __attribute__((ext_vector_type(4)));   // 16x16 acc
typedef float  f32x16 __attribute__((ext_vector_type(16)));  // 32x32 acc (head)

// ---------------- workspace layout (bytes) ----------------
#define OFF_XBF   ((size_t)0)                      // B*T*F bf16 = 8 MB
#define OFF_WOUT  ((size_t)(8u<<20))               // O*H bf16 = 128 KB
#define OFF_SEQ0  ((size_t)(12u<<20))              // B*T*H bf16 = 32 MB
#define OFF_SEQ1  (OFF_SEQ0 + ((size_t)32u<<20))
#define OFF_SEQ2  (OFF_SEQ1 + ((size_t)32u<<20))
#define OFF_FLAGS (OFF_SEQ2 + ((size_t)32u<<20))   // 12 lines x 16 dwords

// LDS: 96 KB rec weights + 2 A-tiles + xp/rz buffers + hout = 146 KB
//  -> 1 WG per CU (160 KB pool), forced naturally.
#define SMEM_BYTES 149504

__device__ __forceinline__ unsigned short f2bf(float f) {
  unsigned int u = __float_as_uint(f);
  u += 0x7fffu + ((u >> 16) & 1u);   // RNE
  return (unsigned short)(u >> 16);
}

__device__ __forceinline__ unsigned int ld_flag(unsigned int* p) {
  return __hip_atomic_load(p, __ATOMIC_RELAXED, __HIP_MEMORY_SCOPE_AGENT);
}

// poll 4 consecutive flag slots until min >= tgt (call from lanes 0..3)
__device__ __forceinline__ void poll4(unsigned int* line, int j, unsigned int tgt) {
  unsigned int* p = line + j*4;
  for (;;) {
    unsigned int a = ld_flag(p+0), b = ld_flag(p+1);
    unsigned int c = ld_flag(p+2), d = ld_flag(p+3);
    unsigned int m = min(min(a,b), min(c,d));
    if (m >= tgt) break;
    __builtin_amdgcn_s_sleep(1);
  }
}

__device__ __forceinline__ float sigmoid_f(float x) { return 1.f / (1.f + __expf(-x)); }
__device__ __forceinline__ float tanh_f(float x)    { return 1.f - 2.f / (__expf(2.f*x) + 1.f); }

// ---------------------------------------------------------------------------
// Persistent wavefront-pipelined GRU — r0 protocol EXACTLY, plus one change:
// rec-gate weights live in LDS (written once at startup in MFMA-fragment
// layout). r0's VGPR_Count=108 proved the old "register preload" never was
// resident: every wave re-streamed 32 KB of weights from L1/L2 EVERY STEP
// (~192 KB/WG/step), which dominated phase 1 and made all exchange-protocol
// tuning (r2-r5) irrelevant. Now phase 1 is pure LDS->MFMA for rec waves;
// xp waves keep register weights, which now fit (rec waves freed the
// pressure; kernel peak ~200 VGPR < 256 needed for 2 waves/SIMD).
// ---------------------------------------------------------------------------
__global__ __launch_bounds__(384, 1)
void gru_persist(const unsigned short* __restrict__ xbf,
                 unsigned short* __restrict__ seq0,
                 unsigned short* __restrict__ seq1,
                 unsigned short* __restrict__ seq2,
                 unsigned int* __restrict__ flags,
                 const float* __restrict__ Wih0, const float* __restrict__ Whh0,
                 const float* __restrict__ bih0, const float* __restrict__ bhh0,
                 const float* __restrict__ Wih1, const float* __restrict__ Whh1,
                 const float* __restrict__ bih1, const float* __restrict__ bhh1,
                 const float* __restrict__ Wih2, const float* __restrict__ Whh2,
                 const float* __restrict__ bih2, const float* __restrict__ bhh2)
{
  extern __shared__ char smem[];
  unsigned short* WLs = (unsigned short*)smem;                 // 96 KB rec weights
  unsigned short* hA  = (unsigned short*)(smem + 98304);       // 16 x 520 shorts
  unsigned short* xA  = (unsigned short*)(smem + 114944);      // 16 x 520 shorts
  float (*xpL)[3][16][33] = (float (*)[3][16][33])(smem + 131584); // 2 slots
  float (*rzL)[16][33]    = (float (*)[16][33])(smem + 144256);    // r/z
  unsigned short* hout    = (unsigned short*)(smem + 148480);      // 1 KB

  const int tid  = threadIdx.x;
  const int wid  = tid >> 6;
  const int lane = tid & 63;
  const int col  = lane & 15;     // n / m index
  const int quad = lane >> 4;     // k-group / row-quad

  const int wg = blockIdx.x;
  const int l  = wg >> 6;          // layer 0..2
  const int rr = wg & 63;
  const int bq = rr >> 4;          // batch quarter
  const int cq = rr & 15;          // col slice
  const int c0 = cq * 32;
  const int b0 = bq * 16;

  unsigned short* seqw = (l==0) ? seq0 : (l==1) ? seq1 : seq2;
  const unsigned short* seqr = (l==1) ? seq0 : (l==2) ? seq1 : (const unsigned short*)0;

  const bool isrec = (wid < 3);
  const int  g     = isrec ? wid : wid - 3;

  const float* Whh = (l==0)?Whh0:(l==1)?Whh1:Whh2;
  const float* Wih = (l==0)?Wih0:(l==1)?Wih1:Wih2;
  const float* bhh = (l==0)?bhh0:(l==1)?bhh1:bhh2;
  const float* bih = (l==0)?bih0:(l==1)?bih1:bih2;

  const float* Wsrc = isrec ? Whh : Wih;
  const int K   = isrec ? NH : ((l==0) ? NF : NH);
  const int KT  = K >> 5;                 // 16 (K=512) or 4 (K=128)
  const int KTx = (l==0) ? 4 : 16;        // xp tile count
  const int xrow = (l==0) ? NF : NH;      // xp source row length (shorts)

  // ---- weight residency ----
  // rec waves: gate slice -> LDS, exact per-lane fragment layout.
  //   frag (g, kt, j) base short index = ((g*16+kt)*2+j)*512; lane owns +lane*8.
  // xp waves: register arrays (rec waves freed the VGPR budget).
  s16x8 wr0[16], wr1[16];
  if (isrec) {
    #pragma unroll
    for (int kt = 0; kt < 16; ++kt) {
      #pragma unroll
      for (int j = 0; j < 2; ++j) {
        const float* s = Wsrc + (size_t)(g*NH + c0 + j*16 + col) * NH + kt*32 + quad*8;
        s16x8 w;
        #pragma unroll
        for (int jj = 0; jj < 8; ++jj) w[jj] = (short)f2bf(s[jj]);
        *(s16x8*)&WLs[((g*16 + kt)*2 + j)*512 + lane*8] = w;
      }
    }
  } else {
    #pragma unroll
    for (int kt = 0; kt < 16; ++kt) {
      if (kt < KT) {
        const float* s0 = Wsrc + (size_t)(g*NH + c0 +      col) * K + kt*32 + quad*8;
        const float* s1 = Wsrc + (size_t)(g*NH + c0 + 16 + col) * K + kt*32 + quad*8;
        s16x8 w0, w1;
        #pragma unroll
        for (int j = 0; j < 8; ++j) { w0[j] = (short)f2bf(s0[j]); w1[j] = (short)f2bf(s1[j]); }
        wr0[kt] = w0; wr1[kt] = w1;
      } else { wr0[kt] = (s16x8)0; wr1[kt] = (s16x8)0; }
    }
  }
  const float* bb = isrec ? bhh : bih;
  const float bias0 = bb[g*NH + c0 +      col];
  const float bias1 = bb[g*NH + c0 + 16 + col];

  unsigned int* line_self = flags + (size_t)(l*4 + bq)*16;
  unsigned int* line_prev = (l > 0) ? (flags + (size_t)((l-1)*4 + bq)*16) : line_self;

  // stage a 16-row A-tile (rows b0..b0+15, time `step`) into LDS.
  // Called by a wave pair (half = 0/1 -> rows 0-7 / 8-15), 8 lanes per row.
  auto stage_tile = [&](unsigned short* dst, const unsigned short* srcbase,
                        int rowlen, int step, int half) {
    const int sr = (half << 3) + (lane >> 3);
    const int sc = lane & 7;
    const unsigned short* src = srcbase + ((size_t)(b0 + sr)*NT + step)*rowlen;
    const int nld = rowlen >> 6;        // 512 -> 8, 128 -> 2 (16B granules/lane)
    s16x8 tmp[8];
    #pragma unroll
    for (int i = 0; i < 8; ++i) if (i < nld) tmp[i] = *(const s16x8*)(src + (i*8 + sc)*8);
    #pragma unroll
    for (int i = 0; i < 8; ++i) if (i < nld) *(s16x8*)&dst[sr*HSTR + (i*8 + sc)*8] = tmp[i];
  };

  // ---- prologue ----
  if (!isrec) {
    // xp(0) computed directly from global -> xpL[0]
    if (l > 0 && lane < 4) poll4(line_prev, lane, 1u);
    asm volatile("" ::: "memory");
    f32x4 a0 = {0.f,0.f,0.f,0.f}, a1 = {0.f,0.f,0.f,0.f};
    const unsigned short* ar = (l==0)
        ? xbf  + (size_t)(b0+col)*NT*NF + quad*8
        : seqr + (size_t)(b0+col)*NT*NH + quad*8;
    #pragma unroll
    for (int kt = 0; kt < 16; ++kt) if (kt < KTx) {
      s16x8 a = *(const s16x8*)(ar + kt*32);
      a0 = __builtin_amdgcn_mfma_f32_16x16x32_bf16(a, wr0[kt], a0, 0, 0, 0);
      a1 = __builtin_amdgcn_mfma_f32_16x16x32_bf16(a, wr1[kt], a1, 0, 0, 0);
    }
    #pragma unroll
    for (int i = 0; i < 4; ++i) {
      int row = quad*4 + i;
      xpL[0][g][row][col]      = a0[i] + bias0;
      xpL[0][g][row][col + 16] = a1[i] + bias1;
    }
  } else if (wid < 2) {
    // stage xA with step-1 source (consumed by phase 1 of iter 0 -> xp(1))
    if (l > 0 && lane < 4) poll4(line_prev, lane, 2u);
    asm volatile("" ::: "memory");
    stage_tile(xA, (l==0) ? xbf : seqr, xrow, 1, wid);
  }
  __syncthreads();

  float hp0[4] = {0.f,0.f,0.f,0.f}, hp1[4] = {0.f,0.f,0.f,0.f};  // n-wave h state

  for (int t = 0; t < NT; ++t) {
    const int slot  = t & 1;
    const int nslot = slot ^ 1;

    f32x4 a0 = {0.f,0.f,0.f,0.f}, a1 = {0.f,0.f,0.f,0.f};

    // ---------------- phase 1: pure LDS -> MFMA compute ----------------
    if (isrec) {
      if (t > 0) {
        #pragma unroll
        for (int kt = 0; kt < 16; ++kt) {
          s16x8 a  = *(const s16x8*)&hA[col*HSTR + kt*32 + quad*8];
          s16x8 b0 = *(const s16x8*)&WLs[((g*16 + kt)*2 + 0)*512 + lane*8];
          s16x8 b1 = *(const s16x8*)&WLs[((g*16 + kt)*2 + 1)*512 + lane*8];
          a0 = __builtin_amdgcn_mfma_f32_16x16x32_bf16(a, b0, a0, 0, 0, 0);
          a1 = __builtin_amdgcn_mfma_f32_16x16x32_bf16(a, b1, a1, 0, 0, 0);
        }
      }
      if (g < 2) {       // r/z: sigmoid -> LDS
        #pragma unroll
        for (int i = 0; i < 4; ++i) {
          int row = quad*4 + i;
          float p0 = a0[i] + xpL[slot][g][row][col]      + bias0;
          float p1 = a1[i] + xpL[slot][g][row][col + 16] + bias1;
          rzL[g][row][col]      = sigmoid_f(p0);
          rzL[g][row][col + 16] = sigmoid_f(p1);
        }
      } else {           // n: keep pre-activation hn (+bhh_n) in regs
        #pragma unroll
        for (int i = 0; i < 4; ++i) { a0[i] += bias0; a1[i] += bias1; }
      }
    } else if (t + 1 < NT) {   // xp waves: xp(t+1) from xA -> xpL[nslot]
      #pragma unroll
      for (int kt = 0; kt < 16; ++kt) if (kt < KTx) {
        s16x8 a = *(const s16x8*)&xA[col*HSTR + kt*32 + quad*8];
        a0 = __builtin_amdgcn_mfma_f32_16x16x32_bf16(a, wr0[kt], a0, 0, 0, 0);
        a1 = __builtin_amdgcn_mfma_f32_16x16x32_bf16(a, wr1[kt], a1, 0, 0, 0);
      }
      #pragma unroll
      for (int i = 0; i < 4; ++i) {
        int row = quad*4 + i;
        xpL[nslot][g][row][col]      = a0[i] + bias0;
        xpL[nslot][g][row][col + 16] = a1[i] + bias1;
      }
    }
    __syncthreads();   // B1

    // ---------------- phase 2: n-store  ||  poll+stage next tiles ----------
    if (wid == 2) {      // n-wave: gate combine, h update, sc1 store, flag
      #pragma unroll
      for (int i = 0; i < 4; ++i) {
        int row = quad*4 + i;
        float xn0 = xpL[slot][2][row][col];
        float xn1 = xpL[slot][2][row][col + 16];
        float rt0 = rzL[0][row][col],      rt1 = rzL[0][row][col + 16];
        float zt0 = rzL[1][row][col],      zt1 = rzL[1][row][col + 16];
        float nv0 = tanh_f(xn0 + rt0 * a0[i]);
        float nv1 = tanh_f(xn1 + rt1 * a1[i]);
        float h0 = (1.f - zt0)*nv0 + zt0*hp0[i];
        float h1 = (1.f - zt1)*nv1 + zt1*hp1[i];
        hp0[i] = h0; hp1[i] = h1;
        hout[row*32 + col]      = f2bf(h0);
        hout[row*32 + col + 16] = f2bf(h1);
      }
      asm volatile("s_waitcnt lgkmcnt(0)" ::: "memory");
      {
        int srow = lane >> 2, sch = lane & 3;
        s16x8 hv = *(const s16x8*)&hout[srow*32 + sch*8];
        unsigned short* p = seqw + ((size_t)(b0+srow)*NT + t)*NH + c0 + sch*8;
        asm volatile("global_store_dwordx4 %0, %1, off sc0 sc1" :: "v"(p), "v"(hv) : "memory");
        asm volatile("s_waitcnt vmcnt(0)" ::: "memory");   // h at coherence point
      }
      if (lane == 0)
        __hip_atomic_store(line_self + cq, (unsigned)(t + 1),
                           __ATOMIC_RELAXED, __HIP_MEMORY_SCOPE_AGENT);
    } else if (wid < 2) {        // stage hA = h(t) for phase 1 of t+1
      if (t + 1 < NT) {
        if (lane < 4) poll4(line_self, lane, (unsigned)(t + 1));
        asm volatile("" ::: "memory");
        stage_tile(hA, seqw, NH, t, wid);
      }
    } else if (wid == 3 || wid == 4) {   // stage xA = src(t+2) for xp(t+2)
      if (t + 2 < NT) {
        if (l > 0 && lane < 4) poll4(line_prev, lane, (unsigned)(t + 3));
        asm volatile("" ::: "memory");
        stage_tile(xA, (l==0) ? xbf : seqr, xrow, t + 2, wid - 3);
      }
    }
    __syncthreads();   // B2
  }
}

// ---------------- head GEMM: out[bt][o] = seq2[bt][:] . Wout[o][:] + bout ----
__global__ __launch_bounds__(256)
void head_gemm(const unsigned short* __restrict__ seq2,
               const unsigned short* __restrict__ woutb,
               const float* __restrict__ bout,
               float* __restrict__ out)
{
  int tid = threadIdx.x;
  int wv = tid >> 6, lane = tid & 63;
  int col = lane & 31, khi = lane >> 5;
  int id = blockIdx.x*4 + wv;
  int mt = id >> 2, nt = id & 3;
  int m0 = mt*32, n0 = nt*32;
  const unsigned short* arow = seq2  + (size_t)(m0 + col)*NH + (khi << 3);
  const unsigned short* brow = woutb + (size_t)(n0 + col)*NH + (khi << 3);
  f32x16 acc;
  #pragma unroll
  for (int i = 0; i < 16; ++i) acc[i] = 0.f;
  #pragma unroll 8
  for (int kt = 0; kt < 32; ++kt) {
    s16x8 a = *(const s16x8*)(arow + kt*16);
    s16x8 b = *(const s16x8*)(brow + kt*16);
    acc = __builtin_amdgcn_mfma_f32_32x32x16_bf16(a, b, acc, 0, 0, 0);
  }
  float bo = bout[n0 + col];
  #pragma unroll
  for (int r = 0; r < 16; ++r) {
    int row = (r & 3) + ((r >> 2) << 3) + (khi << 2);
    out[(size_t)(m0 + row)*NO + n0 + col] = acc[r] + bo;
  }
}

__global__ void cast_f32_bf16(const float* __restrict__ src,
                              unsigned short* __restrict__ dst, int n) {
  int i = blockIdx.x*blockDim.x + threadIdx.x;
  int stride = gridDim.x*blockDim.x;
  for (; i < n; i += stride) dst[i] = f2bf(src[i]);
}

extern "C" void kernel_launch(void* const* d_in, const int* in_sizes, int n_in,
                              void* d_out, int out_size, void* d_ws, size_t ws_size,
                              hipStream_t stream) {
  (void)in_sizes; (void)n_in; (void)out_size; (void)ws_size;
  const float* x    = (const float*)d_in[0];
  const float* Wih0 = (const float*)d_in[1];
  const float* Whh0 = (const float*)d_in[2];
  const float* bih0 = (const float*)d_in[3];
  const float* bhh0 = (const float*)d_in[4];
  const float* Wih1 = (const float*)d_in[5];
  const float* Whh1 = (const float*)d_in[6];
  const float* bih1 = (const float*)d_in[7];
  const float* bhh1 = (const float*)d_in[8];
  const float* Wih2 = (const float*)d_in[9];
  const float* Whh2 = (const float*)d_in[10];
  const float* bih2 = (const float*)d_in[11];
  const float* bhh2 = (const float*)d_in[12];
  const float* Wout = (const float*)d_in[13];
  const float* bout = (const float*)d_in[14];

  char* ws = (char*)d_ws;
  unsigned short* xbf  = (unsigned short*)(ws + OFF_XBF);
  unsigned short* wob  = (unsigned short*)(ws + OFF_WOUT);
  unsigned short* seq0 = (unsigned short*)(ws + OFF_SEQ0);
  unsigned short* seq1 = (unsigned short*)(ws + OFF_SEQ1);
  unsigned short* seq2 = (unsigned short*)(ws + OFF_SEQ2);
  unsigned int*   flg  = (unsigned int*)(ws + OFF_FLAGS);

  // allow >64KB dynamic LDS (idempotent, capture-safe)
  (void)hipFuncSetAttribute((const void*)gru_persist,
                            hipFuncAttributeMaxDynamicSharedMemorySize, 160*1024);

  hipMemsetAsync(ws + OFF_FLAGS, 0, 4096, stream);
  cast_f32_bf16<<<512, 256, 0, stream>>>(x, xbf, NB*NT*NF);
  cast_f32_bf16<<<64, 256, 0, stream>>>(Wout, wob, NO*NH);
  gru_persist<<<192, 384, SMEM_BYTES, stream>>>(xbf, seq0, seq1, seq2, flg,
      Wih0, Whh0, bih0, bhh0, Wih1, Whh1, bih1, bhh1, Wih2, Whh2, bih2, bhh2);
  head_gemm<<<1024, 256, 0, stream>>>(seq2, wob, bout, (float*)d_out);
}

// Round 7
// 2666.739 us; speedup vs baseline: 1.4042x; 1.1141x over previous
//
#include <hip/hip_runtime.h>
#include <stdint.h>
#include <math.h>

#define NB 64
#define NT 512
#define NF 128
#define NH 512
#define NO 128
#define HSTR 520   // LDS xA-tile row stride in shorts (512 + 8 pad)

typedef short  s16x8  __attribute__((ext_vector_type(8)));   // 8 bf16
typedef float  f32x4  __attribute__((ext_vector_type(4)));   // 16x16 acc
typedef float  f32x16 __attribute__((ext_vector_type(16)));  // 32x32 acc (head)

// ---------------- workspace layout (bytes) ----------------
#define OFF_XBF   ((size_t)0)                      // B*T*F bf16 = 8 MB
#define OFF_WOUT  ((size_t)(8u<<20))               // O*H bf16 = 128 KB
#define OFF_SEQ0  ((size_t)(12u<<20))              // B*T*H bf16 = 32 MB
#define OFF_SEQ1  (OFF_SEQ0 + ((size_t)32u<<20))
#define OFF_SEQ2  (OFF_SEQ1 + ((size_t)32u<<20))
#define OFF_FLAGS (OFF_SEQ2 + ((size_t)32u<<20))   // 12 lines x 16 dwords

// LDS: 96 KB rec weights + xA tile + xp/rz buffers + hout = ~130 KB
//  -> 1 WG per CU (160 KB pool).
#define SMEM_BYTES 133120

__device__ __forceinline__ unsigned short f2bf(float f) {
  unsigned int u = __float_as_uint(f);
  u += 0x7fffu + ((u >> 16) & 1u);   // RNE
  return (unsigned short)(u >> 16);
}

__device__ __forceinline__ unsigned int ld_flag(unsigned int* p) {
  return __hip_atomic_load(p, __ATOMIC_RELAXED, __HIP_MEMORY_SCOPE_AGENT);
}

// poll 4 consecutive flag slots until min >= tgt (call from lanes 0..3)
__device__ __forceinline__ void poll4(unsigned int* line, int j, unsigned int tgt) {
  unsigned int* p = line + j*4;
  for (;;) {
    unsigned int a = ld_flag(p+0), b = ld_flag(p+1);
    unsigned int c = ld_flag(p+2), d = ld_flag(p+3);
    unsigned int m = min(min(a,b), min(c,d));
    if (m >= tgt) break;
    __builtin_amdgcn_s_sleep(1);
  }
}

__device__ __forceinline__ float sigmoid_f(float x) { return 1.f / (1.f + __expf(-x)); }
__device__ __forceinline__ float tanh_f(float x)    { return 1.f - 2.f / (__expf(2.f*x) + 1.f); }

// ---------------------------------------------------------------------------
// Persistent wavefront-pipelined GRU — r0/r6 protocol, with the hA staging
// hop REMOVED: rec waves poll the group flags at the top of phase 1 and load
// their h(t-1) A-fragments DIRECTLY from global into registers (16 x 16B per
// lane), then MFMA against LDS-resident weights. This deletes the per-step
// LLC->LDS->regs staging pipeline (stage BW + ds_write/ds_read + hA bank
// conflicts + the B2->phase1 ordering) from the recurrence critical path.
// xA staging, wave-2 epilogue/store/flag, and all flag semantics unchanged.
// ---------------------------------------------------------------------------
__global__ __launch_bounds__(384, 1)
void gru_persist(const unsigned short* __restrict__ xbf,
                 unsigned short* __restrict__ seq0,
                 unsigned short* __restrict__ seq1,
                 unsigned short* __restrict__ seq2,
                 unsigned int* __restrict__ flags,
                 const float* __restrict__ Wih0, const float* __restrict__ Whh0,
                 const float* __restrict__ bih0, const float* __restrict__ bhh0,
                 const float* __restrict__ Wih1, const float* __restrict__ Whh1,
                 const float* __restrict__ bih1, const float* __restrict__ bhh1,
                 const float* __restrict__ Wih2, const float* __restrict__ Whh2,
                 const float* __restrict__ bih2, const float* __restrict__ bhh2)
{
  extern __shared__ char smem[];
  unsigned short* WLs = (unsigned short*)smem;                 // 96 KB rec weights
  unsigned short* xA  = (unsigned short*)(smem + 98304);       // 16 x 520 shorts
  float (*xpL)[3][16][33] = (float (*)[3][16][33])(smem + 114944); // 2 slots
  float (*rzL)[16][33]    = (float (*)[16][33])(smem + 127616);    // r/z
  unsigned short* hout    = (unsigned short*)(smem + 131840);      // 1 KB

  const int tid  = threadIdx.x;
  const int wid  = tid >> 6;
  const int lane = tid & 63;
  const int col  = lane & 15;     // n / m index
  const int quad = lane >> 4;     // k-group / row-quad

  const int wg = blockIdx.x;
  const int l  = wg >> 6;          // layer 0..2
  const int rr = wg & 63;
  const int bq = rr >> 4;          // batch quarter
  const int cq = rr & 15;          // col slice
  const int c0 = cq * 32;
  const int b0 = bq * 16;

  unsigned short* seqw = (l==0) ? seq0 : (l==1) ? seq1 : seq2;
  const unsigned short* seqr = (l==1) ? seq0 : (l==2) ? seq1 : (const unsigned short*)0;

  const bool isrec = (wid < 3);
  const int  g     = isrec ? wid : wid - 3;

  const float* Whh = (l==0)?Whh0:(l==1)?Whh1:Whh2;
  const float* Wih = (l==0)?Wih0:(l==1)?Wih1:Wih2;
  const float* bhh = (l==0)?bhh0:(l==1)?bhh1:bhh2;
  const float* bih = (l==0)?bih0:(l==1)?bih1:bih2;

  const float* Wsrc = isrec ? Whh : Wih;
  const int K   = isrec ? NH : ((l==0) ? NF : NH);
  const int KT  = K >> 5;                 // 16 (K=512) or 4 (K=128)
  const int KTx = (l==0) ? 4 : 16;        // xp tile count
  const int xrow = (l==0) ? NF : NH;      // xp source row length (shorts)

  // ---- weight residency ----
  // rec waves: gate slice -> LDS in MFMA-fragment layout (r6, proven).
  // xp waves: register arrays (compiler may stream; xp is off-critical).
  s16x8 wr0[16], wr1[16];
  if (isrec) {
    #pragma unroll
    for (int kt = 0; kt < 16; ++kt) {
      #pragma unroll
      for (int j = 0; j < 2; ++j) {
        const float* s = Wsrc + (size_t)(g*NH + c0 + j*16 + col) * NH + kt*32 + quad*8;
        s16x8 w;
        #pragma unroll
        for (int jj = 0; jj < 8; ++jj) w[jj] = (short)f2bf(s[jj]);
        *(s16x8*)&WLs[((g*16 + kt)*2 + j)*512 + lane*8] = w;
      }
    }
  } else {
    #pragma unroll
    for (int kt = 0; kt < 16; ++kt) {
      if (kt < KT) {
        const float* s0 = Wsrc + (size_t)(g*NH + c0 +      col) * K + kt*32 + quad*8;
        const float* s1 = Wsrc + (size_t)(g*NH + c0 + 16 + col) * K + kt*32 + quad*8;
        s16x8 w0, w1;
        #pragma unroll
        for (int j = 0; j < 8; ++j) { w0[j] = (short)f2bf(s0[j]); w1[j] = (short)f2bf(s1[j]); }
        wr0[kt] = w0; wr1[kt] = w1;
      } else { wr0[kt] = (s16x8)0; wr1[kt] = (s16x8)0; }
    }
  }
  const float* bb = isrec ? bhh : bih;
  const float bias0 = bb[g*NH + c0 +      col];
  const float bias1 = bb[g*NH + c0 + 16 + col];

  unsigned int* line_self = flags + (size_t)(l*4 + bq)*16;
  unsigned int* line_prev = (l > 0) ? (flags + (size_t)((l-1)*4 + bq)*16) : line_self;

  // stage a 16-row A-tile (rows b0..b0+15, time `step`) into LDS (xA only).
  auto stage_tile = [&](unsigned short* dst, const unsigned short* srcbase,
                        int rowlen, int step, int half) {
    const int sr = (half << 3) + (lane >> 3);
    const int sc = lane & 7;
    const unsigned short* src = srcbase + ((size_t)(b0 + sr)*NT + step)*rowlen;
    const int nld = rowlen >> 6;        // 512 -> 8, 128 -> 2 (16B granules/lane)
    s16x8 tmp[8];
    #pragma unroll
    for (int i = 0; i < 8; ++i) if (i < nld) tmp[i] = *(const s16x8*)(src + (i*8 + sc)*8);
    #pragma unroll
    for (int i = 0; i < 8; ++i) if (i < nld) *(s16x8*)&dst[sr*HSTR + (i*8 + sc)*8] = tmp[i];
  };

  // ---- prologue ----
  if (!isrec) {
    // xp(0) computed directly from global -> xpL[0]
    if (l > 0 && lane < 4) poll4(line_prev, lane, 1u);
    asm volatile("" ::: "memory");
    f32x4 a0 = {0.f,0.f,0.f,0.f}, a1 = {0.f,0.f,0.f,0.f};
    const unsigned short* ar = (l==0)
        ? xbf  + (size_t)(b0+col)*NT*NF + quad*8
        : seqr + (size_t)(b0+col)*NT*NH + quad*8;
    #pragma unroll
    for (int kt = 0; kt < 16; ++kt) if (kt < KTx) {
      s16x8 a = *(const s16x8*)(ar + kt*32);
      a0 = __builtin_amdgcn_mfma_f32_16x16x32_bf16(a, wr0[kt], a0, 0, 0, 0);
      a1 = __builtin_amdgcn_mfma_f32_16x16x32_bf16(a, wr1[kt], a1, 0, 0, 0);
    }
    #pragma unroll
    for (int i = 0; i < 4; ++i) {
      int row = quad*4 + i;
      xpL[0][g][row][col]      = a0[i] + bias0;
      xpL[0][g][row][col + 16] = a1[i] + bias1;
    }
  } else if (wid < 2) {
    // stage xA with step-1 source (consumed by phase 1 of iter 0 -> xp(1))
    if (l > 0 && lane < 4) poll4(line_prev, lane, 2u);
    asm volatile("" ::: "memory");
    stage_tile(xA, (l==0) ? xbf : seqr, xrow, 1, wid);
  }
  __syncthreads();

  float hp0[4] = {0.f,0.f,0.f,0.f}, hp1[4] = {0.f,0.f,0.f,0.f};  // n-wave h state

  for (int t = 0; t < NT; ++t) {
    const int slot  = t & 1;
    const int nslot = slot ^ 1;

    f32x4 a0 = {0.f,0.f,0.f,0.f}, a1 = {0.f,0.f,0.f,0.f};

    // ---------------- phase 1 ----------------
    if (isrec) {
      if (t > 0) {
        // poll group flags >= t  (h(t-1) at coherence point), then load
        // A-fragments of h(t-1) DIRECTLY from global into registers.
        if (lane < 4) poll4(line_self, lane, (unsigned)t);
        asm volatile("" ::: "memory");
        const unsigned short* hsrc =
            seqw + ((size_t)(b0 + col)*NT + (t - 1))*NH + quad*8;
        s16x8 af[16];
        #pragma unroll
        for (int kt = 0; kt < 16; ++kt) af[kt] = *(const s16x8*)(hsrc + kt*32);
        #pragma unroll
        for (int kt = 0; kt < 16; ++kt) {
          s16x8 b0w = *(const s16x8*)&WLs[((g*16 + kt)*2 + 0)*512 + lane*8];
          s16x8 b1w = *(const s16x8*)&WLs[((g*16 + kt)*2 + 1)*512 + lane*8];
          a0 = __builtin_amdgcn_mfma_f32_16x16x32_bf16(af[kt], b0w, a0, 0, 0, 0);
          a1 = __builtin_amdgcn_mfma_f32_16x16x32_bf16(af[kt], b1w, a1, 0, 0, 0);
        }
      }
      if (g < 2) {       // r/z: sigmoid -> LDS
        #pragma unroll
        for (int i = 0; i < 4; ++i) {
          int row = quad*4 + i;
          float p0 = a0[i] + xpL[slot][g][row][col]      + bias0;
          float p1 = a1[i] + xpL[slot][g][row][col + 16] + bias1;
          rzL[g][row][col]      = sigmoid_f(p0);
          rzL[g][row][col + 16] = sigmoid_f(p1);
        }
      } else {           // n: keep pre-activation hn (+bhh_n) in regs
        #pragma unroll
        for (int i = 0; i < 4; ++i) { a0[i] += bias0; a1[i] += bias1; }
      }
    } else if (t + 1 < NT) {   // xp waves: xp(t+1) from xA -> xpL[nslot]
      #pragma unroll
      for (int kt = 0; kt < 16; ++kt) if (kt < KTx) {
        s16x8 a = *(const s16x8*)&xA[col*HSTR + kt*32 + quad*8];
        a0 = __builtin_amdgcn_mfma_f32_16x16x32_bf16(a, wr0[kt], a0, 0, 0, 0);
        a1 = __builtin_amdgcn_mfma_f32_16x16x32_bf16(a, wr1[kt], a1, 0, 0, 0);
      }
      #pragma unroll
      for (int i = 0; i < 4; ++i) {
        int row = quad*4 + i;
        xpL[nslot][g][row][col]      = a0[i] + bias0;
        xpL[nslot][g][row][col + 16] = a1[i] + bias1;
      }
    }
    __syncthreads();   // B1

    // ---------------- phase 2: n-store || stage xA ----------
    if (wid == 2) {      // n-wave: gate combine, h update, sc1 store, flag
      #pragma unroll
      for (int i = 0; i < 4; ++i) {
        int row = quad*4 + i;
        float xn0 = xpL[slot][2][row][col];
        float xn1 = xpL[slot][2][row][col + 16];
        float rt0 = rzL[0][row][col],      rt1 = rzL[0][row][col + 16];
        float zt0 = rzL[1][row][col],      zt1 = rzL[1][row][col + 16];
        float nv0 = tanh_f(xn0 + rt0 * a0[i]);
        float nv1 = tanh_f(xn1 + rt1 * a1[i]);
        float h0 = (1.f - zt0)*nv0 + zt0*hp0[i];
        float h1 = (1.f - zt1)*nv1 + zt1*hp1[i];
        hp0[i] = h0; hp1[i] = h1;
        hout[row*32 + col]      = f2bf(h0);
        hout[row*32 + col + 16] = f2bf(h1);
      }
      asm volatile("s_waitcnt lgkmcnt(0)" ::: "memory");
      {
        int srow = lane >> 2, sch = lane & 3;
        s16x8 hv = *(const s16x8*)&hout[srow*32 + sch*8];
        unsigned short* p = seqw + ((size_t)(b0+srow)*NT + t)*NH + c0 + sch*8;
        asm volatile("global_store_dwordx4 %0, %1, off sc0 sc1" :: "v"(p), "v"(hv) : "memory");
        asm volatile("s_waitcnt vmcnt(0)" ::: "memory");   // h at coherence point
      }
      if (lane == 0)
        __hip_atomic_store(line_self + cq, (unsigned)(t + 1),
                           __ATOMIC_RELAXED, __HIP_MEMORY_SCOPE_AGENT);
    } else if (wid == 3 || wid == 4) {   // stage xA = src(t+2) for xp(t+2)
      if (t + 2 < NT) {
        if (l > 0 && lane < 4) poll4(line_prev, lane, (unsigned)(t + 3));
        asm volatile("" ::: "memory");
        stage_tile(xA, (l==0) ? xbf : seqr, xrow, t + 2, wid - 3);
      }
    }
    // waves 0,1,5: nothing in phase 2 (hA staging removed)
    __syncthreads();   // B2
  }
}

// ---------------- head GEMM: out[bt][o] = seq2[bt][:] . Wout[o][:] + bout ----
__global__ __launch_bounds__(256)
void head_gemm(const unsigned short* __restrict__ seq2,
               const unsigned short* __restrict__ woutb,
               const float* __restrict__ bout,
               float* __restrict__ out)
{
  int tid = threadIdx.x;
  int wv = tid >> 6, lane = tid & 63;
  int col = lane & 31, khi = lane >> 5;
  int id = blockIdx.x*4 + wv;
  int mt = id >> 2, nt = id & 3;
  int m0 = mt*32, n0 = nt*32;
  const unsigned short* arow = seq2  + (size_t)(m0 + col)*NH + (khi << 3);
  const unsigned short* brow = woutb + (size_t)(n0 + col)*NH + (khi << 3);
  f32x16 acc;
  #pragma unroll
  for (int i = 0; i < 16; ++i) acc[i] = 0.f;
  #pragma unroll 8
  for (int kt = 0; kt < 32; ++kt) {
    s16x8 a = *(const s16x8*)(arow + kt*16);
    s16x8 b = *(const s16x8*)(brow + kt*16);
    acc = __builtin_amdgcn_mfma_f32_32x32x16_bf16(a, b, acc, 0, 0, 0);
  }
  float bo = bout[n0 + col];
  #pragma unroll
  for (int r = 0; r < 16; ++r) {
    int row = (r & 3) + ((r >> 2) << 3) + (khi << 2);
    out[(size_t)(m0 + row)*NO + n0 + col] = acc[r] + bo;
  }
}

__global__ void cast_f32_bf16(const float* __restrict__ src,
                              unsigned short* __restrict__ dst, int n) {
  int i = blockIdx.x*blockDim.x + threadIdx.x;
  int stride = gridDim.x*blockDim.x;
  for (; i < n; i += stride) dst[i] = f2bf(src[i]);
}

extern "C" void kernel_launch(void* const* d_in, const int* in_sizes, int n_in,
                              void* d_out, int out_size, void* d_ws, size_t ws_size,
                              hipStream_t stream) {
  (void)in_sizes; (void)n_in; (void)out_size; (void)ws_size;
  const float* x    = (const float*)d_in[0];
  const float* Wih0 = (const float*)d_in[1];
  const float* Whh0 = (const float*)d_in[2];
  const float* bih0 = (const float*)d_in[3];
  const float* bhh0 = (const float*)d_in[4];
  const float* Wih1 = (const float*)d_in[5];
  const float* Whh1 = (const float*)d_in[6];
  const float* bih1 = (const float*)d_in[7];
  const float* bhh1 = (const float*)d_in[8];
  const float* Wih2 = (const float*)d_in[9];
  const float* Whh2 = (const float*)d_in[10];
  const float* bih2 = (const float*)d_in[11];
  const float* bhh2 = (const float*)d_in[12];
  const float* Wout = (const float*)d_in[13];
  const float* bout = (const float*)d_in[14];

  char* ws = (char*)d_ws;
  unsigned short* xbf  = (unsigned short*)(ws + OFF_XBF);
  unsigned short* wob  = (unsigned short*)(ws + OFF_WOUT);
  unsigned short* seq0 = (unsigned short*)(ws + OFF_SEQ0);
  unsigned short* seq1 = (unsigned short*)(ws + OFF_SEQ1);
  unsigned short* seq2 = (unsigned short*)(ws + OFF_SEQ2);
  unsigned int*   flg  = (unsigned int*)(ws + OFF_FLAGS);

  // allow >64KB dynamic LDS (idempotent, capture-safe)
  (void)hipFuncSetAttribute((const void*)gru_persist,
                            hipFuncAttributeMaxDynamicSharedMemorySize, 160*1024);

  hipMemsetAsync(ws + OFF_FLAGS, 0, 4096, stream);
  cast_f32_bf16<<<512, 256, 0, stream>>>(x, xbf, NB*NT*NF);
  cast_f32_bf16<<<64, 256, 0, stream>>>(Wout, wob, NO*NH);
  gru_persist<<<192, 384, SMEM_BYTES, stream>>>(xbf, seq0, seq1, seq2, flg,
      Wih0, Whh0, bih0, bhh0, Wih1, Whh1, bih1, bhh1, Wih2, Whh2, bih2, bhh2);
  head_gemm<<<1024, 256, 0, stream>>>(seq2, wob, bout, (float*)d_out);
}